// Round 1
// baseline (1675.948 us; speedup 1.0000x reference)
//
#include <hip/hip_runtime.h>

// MPM P2G scatter: 1M particles -> 128^3 grid, trilinear (2^3) stencil.
// Output [C,4] interleaved: (mass, mom.x, mom.y, mom.z) per cell.
// hash = gz + gx*128 + gy*128*128  (per reference get_hash, dim==3)

#define GRID_DIM   128
#define NUM_CELLS  (GRID_DIM * GRID_DIM * GRID_DIM)
#define INV_CELL   64.0f

__global__ __launch_bounds__(256) void p2g_scatter_kernel(
    const float* __restrict__ pos,   // [N,3]
    const float* __restrict__ vel,   // [N,3]
    const float* __restrict__ mass,  // [N]
    float* __restrict__ out,         // [NUM_CELLS,4]
    int n)
{
    int i = blockIdx.x * blockDim.x + threadIdx.x;
    if (i >= n) return;

    // Position in cell units (ORIGIN = 0)
    float px = pos[3 * i + 0] * INV_CELL;
    float py = pos[3 * i + 1] * INV_CELL;
    float pz = pos[3 * i + 2] * INV_CELL;

    float bx = floorf(px), by = floorf(py), bz = floorf(pz);
    float fx = px - bx, fy = py - by, fz = pz - bz;
    int ix = (int)bx, iy = (int)by, iz = (int)bz;

    float m  = mass[i];
    float vx = vel[3 * i + 0];
    float vy = vel[3 * i + 1];
    float vz = vel[3 * i + 2];

    // Trilinear weights: offset 0 -> (1-frac), offset 1 -> frac
    float wx[2] = { 1.0f - fx, fx };
    float wy[2] = { 1.0f - fy, fy };
    float wz[2] = { 1.0f - fz, fz };

    #pragma unroll
    for (int a = 0; a < 2; ++a) {
        #pragma unroll
        for (int b = 0; b < 2; ++b) {
            #pragma unroll
            for (int c = 0; c < 2; ++c) {
                int h = (iz + c) + (ix + a) * GRID_DIM
                      + (iy + b) * (GRID_DIM * GRID_DIM);
                // Reference semantics: shapef zeroed if hash out of range,
                // hash clipped for the scatter. (Dead path for this data —
                // particles stay >=1 cell inside the boundary — but cheap.)
                bool valid = (h >= 0) && (h < NUM_CELLS);
                int hc = min(max(h, 0), NUM_CELLS - 1);
                float s = valid ? (wx[a] * wy[b] * wz[c]) : 0.0f;
                float sm = s * m;

                float* cell = out + 4 * (size_t)hc;
                atomicAdd(cell + 0, sm);
                atomicAdd(cell + 1, sm * vx);
                atomicAdd(cell + 2, sm * vy);
                atomicAdd(cell + 3, sm * vz);
            }
        }
    }
}

extern "C" void kernel_launch(void* const* d_in, const int* in_sizes, int n_in,
                              void* d_out, int out_size, void* d_ws, size_t ws_size,
                              hipStream_t stream) {
    const float* pos  = (const float*)d_in[0];  // [N,3]
    const float* vel  = (const float*)d_in[1];  // [N,3]
    const float* mass = (const float*)d_in[2];  // [N]
    float* out = (float*)d_out;                 // [NUM_CELLS,4]

    int n = in_sizes[2];  // mass count == N

    // d_out is poisoned with 0xAA before every timed launch — zero it.
    hipMemsetAsync(out, 0, (size_t)out_size * sizeof(float), stream);

    int block = 256;
    int grid = (n + block - 1) / block;
    p2g_scatter_kernel<<<grid, block, 0, stream>>>(pos, vel, mass, out, n);
}

// Round 2
// 372.297 us; speedup vs baseline: 4.5016x; 4.5016x over previous
//
#include <hip/hip_runtime.h>

// MPM P2G: counting-sort particles into 8^3-cell bins, then per-tile LDS
// gather with plain coalesced stores. Eliminates all global atomics on d_out.
// hash = gz + gx*128 + gy*128*128  (reference get_hash, dim==3)

#define GRID_DIM   128
#define NUM_CELLS  (GRID_DIM * GRID_DIM * GRID_DIM)
#define INV_CELL   64.0f
#define TILE       8                       // cells per tile edge
#define NTILE      (GRID_DIM / TILE)       // 16 tiles per edge
#define NBINS      (NTILE * NTILE * NTILE) // 4096
#define NCOPY      8                       // sub-segments per bin (atomic spread)
#define NBINSF     (NBINS * NCOPY)         // 32768

__device__ __forceinline__ int bin_of(int ix, int iy, int iz) {
    return ((iy >> 3) * NTILE + (ix >> 3)) * NTILE + (iz >> 3);
}

// ---- K1: histogram into 8-way-split bin counters -------------------------
__global__ __launch_bounds__(256) void hist_kernel(
    const float* __restrict__ pos, int* __restrict__ countsF, int n)
{
    int i = blockIdx.x * 256 + threadIdx.x;
    if (i >= n) return;
    int ix = (int)floorf(pos[3 * i + 0] * INV_CELL);
    int iy = (int)floorf(pos[3 * i + 1] * INV_CELL);
    int iz = (int)floorf(pos[3 * i + 2] * INV_CELL);
    ix = min(max(ix, 0), GRID_DIM - 1);
    iy = min(max(iy, 0), GRID_DIM - 1);
    iz = min(max(iz, 0), GRID_DIM - 1);
    int bf = bin_of(ix, iy, iz) * NCOPY + (threadIdx.x & (NCOPY - 1));
    atomicAdd(&countsF[bf], 1);
}

// ---- K2: exclusive scan of 32768 counters (single block) -----------------
__global__ __launch_bounds__(1024) void scan_kernel(
    const int* __restrict__ countsF, int* __restrict__ offsetsF,
    int* __restrict__ cursorsF)
{
    __shared__ int sums[1024];
    const int ITEMS = NBINSF / 1024;  // 32
    int t = threadIdx.x;
    int base = t * ITEMS;
    int v[ITEMS];
    int s = 0;
    #pragma unroll
    for (int j = 0; j < ITEMS; ++j) { v[j] = countsF[base + j]; s += v[j]; }
    sums[t] = s;
    __syncthreads();
    // Hillis-Steele inclusive scan over 1024 thread-sums
    for (int off = 1; off < 1024; off <<= 1) {
        int x = (t >= off) ? sums[t - off] : 0;
        __syncthreads();
        sums[t] += x;
        __syncthreads();
    }
    int run = sums[t] - s;  // exclusive base for this thread's chunk
    #pragma unroll
    for (int j = 0; j < ITEMS; ++j) {
        offsetsF[base + j] = run;
        cursorsF[base + j] = run;
        run += v[j];
    }
    if (t == 1023) offsetsF[NBINSF] = run;  // total n
}

// ---- K3: place 32B particle records into bin-sorted order ----------------
__global__ __launch_bounds__(256) void binplace_kernel(
    const float* __restrict__ pos, const float* __restrict__ vel,
    const float* __restrict__ mass, int* __restrict__ cursorsF,
    float4* __restrict__ records, int n)
{
    int i = blockIdx.x * 256 + threadIdx.x;
    if (i >= n) return;
    float px = pos[3 * i + 0] * INV_CELL;
    float py = pos[3 * i + 1] * INV_CELL;
    float pz = pos[3 * i + 2] * INV_CELL;
    float bx = floorf(px), by = floorf(py), bz = floorf(pz);
    float fx = px - bx, fy = py - by, fz = pz - bz;
    int ix = min(max((int)bx, 0), GRID_DIM - 1);
    int iy = min(max((int)by, 0), GRID_DIM - 1);
    int iz = min(max((int)bz, 0), GRID_DIM - 1);

    int bf = bin_of(ix, iy, iz) * NCOPY + (threadIdx.x & (NCOPY - 1));
    int slot = atomicAdd(&cursorsF[bf], 1);

    int packed = ix | (iy << 7) | (iz << 14);
    records[2 * slot + 0] = make_float4(__int_as_float(packed), fx, fy, fz);
    records[2 * slot + 1] = make_float4(mass[i], vel[3 * i + 0],
                                        vel[3 * i + 1], vel[3 * i + 2]);
}

// ---- K4: one block per 8^3 tile; gather from 8 neighbor bins into LDS ----
__global__ __launch_bounds__(256) void gather_kernel(
    const float4* __restrict__ records, const int* __restrict__ offsetsF,
    float4* __restrict__ out)
{
    __shared__ float acc[TILE * TILE * TILE * 4];  // 8 KB
    int tid = threadIdx.x;
    int b = blockIdx.x;
    int tz = b & (NTILE - 1);
    int tx = (b >> 4) & (NTILE - 1);
    int ty = b >> 8;
    int ox = tx * TILE, oy = ty * TILE, oz = tz * TILE;

    for (int j = tid; j < TILE * TILE * TILE * 4; j += 256) acc[j] = 0.0f;
    __syncthreads();

    for (int dy = -1; dy <= 0; ++dy) {
        int sy = ty + dy; if (sy < 0) continue;
        for (int dx = -1; dx <= 0; ++dx) {
            int sx = tx + dx; if (sx < 0) continue;
            // z-bins tz-1 and tz are contiguous in record order: one range
            int z0 = (tz > 0) ? tz - 1 : 0;
            int s0 = (sy * NTILE + sx) * NTILE + z0;
            int s1 = (sy * NTILE + sx) * NTILE + tz;
            int beg = offsetsF[s0 * NCOPY];
            int end = offsetsF[s1 * NCOPY + NCOPY];
            for (int p = beg + tid; p < end; p += 256) {
                float4 r0 = records[2 * p + 0];
                float4 r1 = records[2 * p + 1];
                int packed = __float_as_int(r0.x);
                int ix = packed & 127;
                int iy = (packed >> 7) & 127;
                int iz = (packed >> 14) & 127;
                float fx = r0.y, fy = r0.z, fz = r0.w;
                float m = r1.x, vx = r1.y, vy = r1.z, vz = r1.w;
                int lx0 = ix - ox, ly0 = iy - oy, lz0 = iz - oz;
                float wxm[2] = { (1.0f - fx) * m, fx * m };
                float wy[2]  = { 1.0f - fy, fy };
                float wz[2]  = { 1.0f - fz, fz };
                #pragma unroll
                for (int a = 0; a < 2; ++a) {
                    #pragma unroll
                    for (int b2 = 0; b2 < 2; ++b2) {
                        #pragma unroll
                        for (int c = 0; c < 2; ++c) {
                            int lx = lx0 + a, ly = ly0 + b2, lz = lz0 + c;
                            if ((unsigned)lx < (unsigned)TILE &&
                                (unsigned)ly < (unsigned)TILE &&
                                (unsigned)lz < (unsigned)TILE) {
                                float sm = wxm[a] * wy[b2] * wz[c];
                                int idx = (((ly * TILE + lx) * TILE) + lz) * 4;
                                atomicAdd(&acc[idx + 0], sm);
                                atomicAdd(&acc[idx + 1], sm * vx);
                                atomicAdd(&acc[idx + 2], sm * vy);
                                atomicAdd(&acc[idx + 3], sm * vz);
                            }
                        }
                    }
                }
            }
        }
    }
    __syncthreads();

    // Tiles partition the grid: every cell written exactly once, no memset.
    for (int c = tid; c < TILE * TILE * TILE; c += 256) {
        int lz = c & 7, lx = (c >> 3) & 7, ly = c >> 6;
        float4 val = *(const float4*)&acc[c * 4];
        out[(oz + lz) + (ox + lx) * GRID_DIM + (oy + ly) * (GRID_DIM * GRID_DIM)] = val;
    }
}

// ---- fallback: verified naive atomic scatter (if ws too small) -----------
__global__ __launch_bounds__(256) void p2g_scatter_kernel(
    const float* __restrict__ pos, const float* __restrict__ vel,
    const float* __restrict__ mass, float* __restrict__ out, int n)
{
    int i = blockIdx.x * blockDim.x + threadIdx.x;
    if (i >= n) return;
    float px = pos[3 * i + 0] * INV_CELL;
    float py = pos[3 * i + 1] * INV_CELL;
    float pz = pos[3 * i + 2] * INV_CELL;
    float bx = floorf(px), by = floorf(py), bz = floorf(pz);
    float fx = px - bx, fy = py - by, fz = pz - bz;
    int ix = (int)bx, iy = (int)by, iz = (int)bz;
    float m = mass[i];
    float vx = vel[3 * i + 0], vy = vel[3 * i + 1], vz = vel[3 * i + 2];
    float wx[2] = { 1.0f - fx, fx }, wy[2] = { 1.0f - fy, fy }, wz[2] = { 1.0f - fz, fz };
    #pragma unroll
    for (int a = 0; a < 2; ++a)
        #pragma unroll
        for (int b = 0; b < 2; ++b)
            #pragma unroll
            for (int c = 0; c < 2; ++c) {
                int h = (iz + c) + (ix + a) * GRID_DIM + (iy + b) * (GRID_DIM * GRID_DIM);
                bool valid = (h >= 0) && (h < NUM_CELLS);
                int hc = min(max(h, 0), NUM_CELLS - 1);
                float s = valid ? (wx[a] * wy[b] * wz[c]) : 0.0f;
                float sm = s * m;
                float* cell = out + 4 * (size_t)hc;
                atomicAdd(cell + 0, sm);
                atomicAdd(cell + 1, sm * vx);
                atomicAdd(cell + 2, sm * vy);
                atomicAdd(cell + 3, sm * vz);
            }
}

extern "C" void kernel_launch(void* const* d_in, const int* in_sizes, int n_in,
                              void* d_out, int out_size, void* d_ws, size_t ws_size,
                              hipStream_t stream) {
    const float* pos  = (const float*)d_in[0];
    const float* vel  = (const float*)d_in[1];
    const float* mass = (const float*)d_in[2];
    float* out = (float*)d_out;
    int n = in_sizes[2];

    size_t rec_bytes   = (size_t)n * 32;
    size_t off_counts  = rec_bytes;
    size_t off_offsets = off_counts + (size_t)NBINSF * 4;
    size_t off_cursors = off_offsets + (size_t)(NBINSF + 1) * 4;
    size_t need        = off_cursors + (size_t)NBINSF * 4;

    if (ws_size >= need) {
        char* ws = (char*)d_ws;
        float4* records = (float4*)ws;
        int* countsF  = (int*)(ws + off_counts);
        int* offsetsF = (int*)(ws + off_offsets);
        int* cursorsF = (int*)(ws + off_cursors);

        hipMemsetAsync(countsF, 0, (size_t)NBINSF * 4, stream);
        int blocks = (n + 255) / 256;
        hist_kernel<<<blocks, 256, 0, stream>>>(pos, countsF, n);
        scan_kernel<<<1, 1024, 0, stream>>>(countsF, offsetsF, cursorsF);
        binplace_kernel<<<blocks, 256, 0, stream>>>(pos, vel, mass, cursorsF, records, n);
        gather_kernel<<<NBINS, 256, 0, stream>>>(records, offsetsF, (float4*)out);
    } else {
        hipMemsetAsync(out, 0, (size_t)out_size * sizeof(float), stream);
        int block = 256;
        int grid = (n + block - 1) / block;
        p2g_scatter_kernel<<<grid, block, 0, stream>>>(pos, vel, mass, out, n);
    }
}